// Round 6
// baseline (35.103 us; speedup 1.0000x reference)
//
#include <hip/hip_runtime.h>
#include <math.h>

// ---------------------------------------------------------------------------
// RobustLoss: CVaR (alpha=0.1) best-response with entropy reg (REG=0.1) on
// M = 2^24 f32 values, returning scalar  p.v - REG*KL(p,uniform).
//
// TWO kernels, single data pass:
//   k_hist         : LDS count histogram (1 fma + 1 ds_add per element)
//                    -> 256 per-block partial histograms; zeroes the counter.
//   k_reduce_solve : 128 blocks reduce partials -> gcnt; the LAST block to
//                    finish (device-scope atomic counter, release/acquire)
//                    runs the scan + 65-ary bisection + histogram-moment loss.
// No memset, no cooperative launch; every scratch byte written before read;
// solve executes exactly once per launch with block-independent results.
// ---------------------------------------------------------------------------

#define NBINS 2048
#define HB    256      // hist blocks (partial histograms)
#define RB    128      // reduce blocks (16 bins each)

static constexpr float  F_INVW  = 128.0f;         // 1 / bin width
static constexpr double D_LO    = -8.0;
static constexpr double D_W     = 0.0078125;      // 16 / 2048
static constexpr double D_REG   = 0.1;
static constexpr double D_WR    = 0.078125;       // D_W / D_REG
static constexpr double D_TOL   = 1e-4;
static constexpr double D_LN10  = 2.302585092994045684;

// ---- inline f64 exp: rel err ~1e-14, no libm calls -------------------------
__device__ __forceinline__ double fexp(double x) {
    const double LOG2E = 1.4426950408889634074;
    const double LN2HI = 6.93147180369123816490e-01;
    const double LN2LO = 1.90821492927058770002e-10;
    double n = rint(x * LOG2E);
    double f = fma(-n, LN2HI, x);
    f = fma(-n, LN2LO, f);                 // |f| <= 0.3466
    double p = 2.08767569878681e-09;       // 1/12!
    p = fma(p, f, 2.5052108385441718e-08);
    p = fma(p, f, 2.7557319223985891e-07);
    p = fma(p, f, 2.7557319223985893e-06);
    p = fma(p, f, 2.4801587301587302e-05);
    p = fma(p, f, 1.9841269841269841e-04);
    p = fma(p, f, 1.3888888888888889e-03);
    p = fma(p, f, 8.3333333333333332e-03);
    p = fma(p, f, 4.1666666666666664e-02);
    p = fma(p, f, 1.6666666666666666e-01);
    p = fma(p, f, 5.0e-01);
    double r = fma(f * f, p, f) + 1.0;
    return ldexp(r, (int)n);
}

// ---- inline f64 log: rel err ~1e-13, x > 0 normal ---------------------------
__device__ __forceinline__ double flog(double x) {
    int e;
    double mant = frexp(x, &e);            // [0.5, 1)
    if (mant < 0.70710678118654752) { mant += mant; e -= 1; }
    double u  = (mant - 1.0) / (mant + 1.0);
    double u2 = u * u;
    double p = 1.0 / 13.0;
    p = fma(p, u2, 1.0 / 11.0);
    p = fma(p, u2, 1.0 / 9.0);
    p = fma(p, u2, 1.0 / 7.0);
    p = fma(p, u2, 1.0 / 5.0);
    p = fma(p, u2, 1.0 / 3.0);
    p = fma(p, u2, 1.0);
    return fma((double)e, 0.69314718055994530942, 2.0 * u * p);
}

// ---------------- Kernel A: count histogram -> per-block partials -----------
__global__ __launch_bounds__(1024) void k_hist(const float4* __restrict__ v4, int n4,
                                               unsigned* __restrict__ gpart,
                                               unsigned* __restrict__ counter) {
    __shared__ unsigned h[NBINS];
    for (int i = threadIdx.x; i < NBINS; i += 1024) h[i] = 0u;
    __syncthreads();

    const int stride = gridDim.x * 1024;
    for (int i = blockIdx.x * 1024 + threadIdx.x; i < n4; i += stride) {
        float4 x = v4[i];
        float vals[4] = {x.x, x.y, x.z, x.w};
#pragma unroll
        for (int k = 0; k < 4; ++k) {
            float pos = fmaf(vals[k], F_INVW, 1024.0f);       // (v+8)*128
            pos = fminf(fmaxf(pos, 0.0f), 2047.0f);
            atomicAdd(&h[(int)pos], 1u);
        }
    }
    __syncthreads();
    unsigned* dst = gpart + (size_t)blockIdx.x * NBINS;
    for (int i = threadIdx.x; i < NBINS; i += 1024) dst[i] = h[i];
    // re-arm the completion counter for this launch (visible at kernel boundary)
    if (threadIdx.x == 0) *counter = 0u;
}

// ---------------- Kernel B: reduce partials; last block solves --------------
__global__ __launch_bounds__(256) void k_reduce_solve(const unsigned* __restrict__ gpart,
                                                      unsigned* __restrict__ gcnt,
                                                      unsigned* __restrict__ counter,
                                                      float* __restrict__ out) {
    __shared__ unsigned rc[16][16];
    __shared__ double pc[NBINS];   // inclusive prefix of counts
    __shared__ double ps[NBINS];   // inclusive prefix of S = sum exp(10 v)
    __shared__ double wtc[4], wts[4];
    __shared__ double ra[4], rb[4], rq3[4];
    __shared__ double sh_eta;
    __shared__ int lastf;

    const int t = threadIdx.x;

    // ---- phase 1: reduce HB slices for this block's 16 bins ----
    {
        const int bl  = t & 15;
        const int row = t >> 4;                     // 0..15
        const int bin = blockIdx.x * 16 + bl;
        unsigned c = 0;
        for (int s = row; s < HB; s += 16)
            c += gpart[(size_t)s * NBINS + bin];
        rc[row][bl] = c;
    }
    __syncthreads();
    if (t < 16) {
        unsigned ct = 0;
#pragma unroll
        for (int k = 0; k < 16; ++k) ct += rc[k][t];
        gcnt[blockIdx.x * 16 + t] = ct;
    }

    // ---- completion protocol: last block proceeds to the solve ----
    __threadfence();                                // release gcnt stores
    __syncthreads();
    if (t == 0) lastf = (atomicAdd(counter, 1u) == RB - 1) ? 1 : 0;
    __syncthreads();
    if (!lastf) return;
    __threadfence();                                // acquire side

    // ---- phase 2 (one block, 256 threads): scan + bisection + loss ----
    const int lane = t & 63;
    const int wid  = t >> 6;
    const double ewr = fexp(D_WR);
    const double KS  = (ewr - 1.0) / D_WR;          // uniform-in-bin exp average

    double cc = 0.0, ss = 0.0, thr_c, thr_s;
    {
        unsigned cu[8];
#pragma unroll
        for (int i = 0; i < 8; ++i)
            cu[i] = __hip_atomic_load(&gcnt[t * 8 + i], __ATOMIC_RELAXED,
                                      __HIP_MEMORY_SCOPE_AGENT);
#pragma unroll
        for (int i = 0; i < 8; ++i) {
            const int bin = t * 8 + i;
            double c = (double)cu[i];
            double S = c * KS * fexp(10.0 * (D_LO + (double)bin * D_W));
            cc += c; ss += S;
            pc[bin] = cc; ps[bin] = ss;             // thread-local inclusive
        }
        thr_c = cc; thr_s = ss;
    }
    // intra-wave inclusive scan of thread totals
#pragma unroll
    for (int off = 1; off < 64; off <<= 1) {
        double nc = __shfl_up(cc, off, 64);
        double ns = __shfl_up(ss, off, 64);
        if (lane >= off) { cc += nc; ss += ns; }
    }
    if (lane == 63) { wtc[wid] = cc; wts[wid] = ss; }
    __syncthreads();                                // b1
    {
        double woc = 0.0, wos = 0.0;
        for (int k = 0; k < wid; ++k) { woc += wtc[k]; wos += wts[k]; }
        double exc_c = cc - thr_c + woc;            // prefix before my bins
        double exc_s = ss - thr_s + wos;
#pragma unroll
        for (int i = 0; i < 8; ++i) { pc[t * 8 + i] += exc_c; ps[t * 8 + i] += exc_s; }
    }
    __syncthreads();                                // b2

    const double m    = pc[NBINS - 1];
    const double Stot = ps[NBINS - 1];

    // ---- wave 0: 65-ary bisection for eta ----
    if (t < 64) {
        const double inv_ewrm1 = 1.0 / (ewr - 1.0);
        const double inv_m = 1.0 / m;

        auto feval = [&](double eta) -> double {
            double c = eta + D_REG * D_LN10;        // clamp boundary in v-space
            double Cle, Sle;
            if (c <= D_LO) { Cle = 0.0; Sle = 0.0; }
            else {
                double pos = (c - D_LO) * (1.0 / D_W);
                if (pos >= (double)NBINS) { Cle = m; Sle = Stot; }
                else {
                    int j = (int)pos;
                    double ttf = pos - (double)j;
                    double pcm = j > 0 ? pc[j - 1] : 0.0;
                    double psm = j > 0 ? ps[j - 1] : 0.0;
                    double cj = pc[j] - pcm;
                    double sj = ps[j] - psm;
                    double frac = (fexp(ttf * D_WR) - 1.0) * inv_ewrm1;
                    Cle = pcm + ttf * cj;
                    Sle = psm + frac * sj;
                }
            }
            return 1.0 - (10.0 * (m - Cle) + fexp(-eta * 10.0) * Sle) * inv_m;
        };

        double eta_min = D_REG * (flog(Stot) - flog(m));
        double f_emin  = feval(eta_min);

        double lo = -12.0;   // f(lo) = -9 < 0
        double hi =  20.0;   // f(hi) ~ 1 > 0
        for (int r = 0; r < 4; ++r) {               // bracket -> 32/65^4 ~ 1.8e-6
            double step = (hi - lo) * (1.0 / 65.0);
            double x = lo + step * (double)(t + 1);
            double fx = feval(x);
            unsigned long long mpos = __ballot(fx > 0.0);
            int k = mpos ? __builtin_ctzll(mpos) : 64;
            double nlo = lo + step * (double)k;
            double nhi = (k >= 64) ? hi : lo + step * (double)(k + 1);
            lo = nlo; hi = nhi;
        }
        double eta = 0.5 * (lo + hi);
        if (fabs(f_emin) <= D_TOL) eta = eta_min;
        if (t == 0) sh_eta = eta;
    }
    __syncthreads();                                // b3

    // ---- all 256 threads: loss moment sums (bins recovered from pc/ps) ----
    const double eta  = sh_eta;
    const double MU_W = D_W * ewr / (ewr - 1.0) - D_REG;   // exp-weighted mean offset

    double cb  = eta + D_REG * D_LN10;
    double pos = (cb - D_LO) * (1.0 / D_W);
    pos = fmin(fmax(pos, 0.0), (double)NBINS);
    int jb = (int)pos;                       // boundary bin (== NBINS: none clamped)
    double ttf = pos - (double)jb;

    double Vt = 0.0, Vb = 0.0, Tb = 0.0;
#pragma unroll
    for (int i = 0; i < 8; ++i) {
        const int bin = t * 8 + i;
        double pcm_ = bin ? pc[bin - 1] : 0.0;
        double c    = pc[bin] - pcm_;
        double bb   = D_LO + (double)bin * D_W;
        double vmid = bb + 0.5 * D_W;
        Vt += c * vmid;
        if (bin < jb) {
            double S = ps[bin] - (bin ? ps[bin - 1] : 0.0);
            Vb += c * vmid;
            Tb += S * (bb + MU_W);
        }
    }
#pragma unroll
    for (int off = 32; off >= 1; off >>= 1) {
        Vt += __shfl_down(Vt, off, 64);
        Vb += __shfl_down(Vb, off, 64);
        Tb += __shfl_down(Tb, off, 64);
    }
    if (lane == 0) { ra[wid] = Vt; rb[wid] = Vb; rq3[wid] = Tb; }
    __syncthreads();                                // b4

    if (t == 0) {
        double Vtot = ra[0] + ra[1] + ra[2] + ra[3];
        double Vle  = rb[0] + rb[1] + rb[2] + rb[3];
        double Tle  = rq3[0] + rq3[1] + rq3[2] + rq3[3];
        double pcm = jb > 0 ? pc[jb - 1] : 0.0;
        double psm = jb > 0 ? ps[jb - 1] : 0.0;
        double Cle = pcm, Sle = psm;
        if (jb < NBINS) {                    // boundary-bin partial contributions
            double cj = pc[jb] - pcm;
            double sj = ps[jb] - psm;
            double bbj = D_LO + (double)jb * D_W;
            double x = ttf * D_W;
            double frac = 0.0, mu = 0.0;
            if (x > 1e-14) {
                double e = fexp(x * 10.0);
                frac = (e - 1.0) / (ewr - 1.0);
                mu   = x * e / (e - 1.0) - D_REG;
            }
            Cle += ttf * cj;
            Sle += frac * sj;
            Tle += frac * sj * (bbj + mu);
            Vle += ttf * cj * (bbj + 0.5 * x);
        }
        double em    = fexp(-eta * 10.0);
        double inv_m = 1.0 / m;
        double lnm   = flog(m);
        double Q  = em * Sle + 10.0 * (m - Cle);               // sum q
        double A  = em * Tle + 10.0 * (Vtot - Vle);            // sum q v
        double B  = 10.0 * (em * Tle - eta * em * Sle)         // sum q ln q
                  + 10.0 * D_LN10 * (m - Cle);
        double plogp = B * inv_m - lnm * (Q * inv_m);
        double loss  = A * inv_m - D_REG * (lnm + plogp);
        out[0] = (float)loss;
    }
}

// ---------------------------------------------------------------------------
extern "C" void kernel_launch(void* const* d_in, const int* in_sizes, int n_in,
                              void* d_out, int out_size, void* d_ws, size_t ws_size,
                              hipStream_t stream) {
    const float* v = (const float*)d_in[0];
    const int n  = in_sizes[0];      // 16777216
    const int n4 = n / 4;

    char* ws = (char*)d_ws;
    unsigned* gpart   = (unsigned*)ws;                              // HB*NBINS u32 = 2 MB
    unsigned* gcnt    = (unsigned*)(ws + (size_t)HB * NBINS * 4);   // NBINS u32
    unsigned* counter = gcnt + NBINS;                               // 1 u32

    k_hist        <<<HB, 1024, 0, stream>>>((const float4*)v, n4, gpart, counter);
    k_reduce_solve<<<RB, 256,  0, stream>>>(gpart, gcnt, counter, (float*)d_out);
}

// Round 7
// 32.451 us; speedup vs baseline: 1.0817x; 1.0817x over previous
//
#include <hip/hip_runtime.h>
#include <math.h>

// ---------------------------------------------------------------------------
// RobustLoss: CVaR (alpha=0.1) best-response with entropy reg (REG=0.1) on
// M = 2^24 f32 values, returning scalar  p.v - REG*KL(p,uniform).
//
// TWO kernels, single data pass:
//   k_hist         : LDS count histogram (1 fma + 1 ds_add per element)
//                    -> 512 per-block partial histograms; zeroes the counter.
//   k_reduce_solve : 128 blocks reduce partials -> gcnt (agent-scope sc1
//                    stores); last block (ACQ_REL atomic counter, NO
//                    threadfence/L2-flush) runs scan + bisection + loss.
// ---------------------------------------------------------------------------

#define NBINS 2048
#define HB    512      // hist blocks (partial histograms)
#define RB    128      // reduce blocks (16 bins each)

static constexpr float  F_INVW  = 128.0f;         // 1 / bin width
static constexpr double D_LO    = -8.0;
static constexpr double D_W     = 0.0078125;      // 16 / 2048
static constexpr double D_REG   = 0.1;
static constexpr double D_WR    = 0.078125;       // D_W / D_REG
static constexpr double D_TOL   = 1e-4;
static constexpr double D_LN10  = 2.302585092994045684;

// ---- inline f64 exp: rel err ~1e-14, no libm calls -------------------------
__device__ __forceinline__ double fexp(double x) {
    const double LOG2E = 1.4426950408889634074;
    const double LN2HI = 6.93147180369123816490e-01;
    const double LN2LO = 1.90821492927058770002e-10;
    double n = rint(x * LOG2E);
    double f = fma(-n, LN2HI, x);
    f = fma(-n, LN2LO, f);                 // |f| <= 0.3466
    double p = 2.08767569878681e-09;       // 1/12!
    p = fma(p, f, 2.5052108385441718e-08);
    p = fma(p, f, 2.7557319223985891e-07);
    p = fma(p, f, 2.7557319223985893e-06);
    p = fma(p, f, 2.4801587301587302e-05);
    p = fma(p, f, 1.9841269841269841e-04);
    p = fma(p, f, 1.3888888888888889e-03);
    p = fma(p, f, 8.3333333333333332e-03);
    p = fma(p, f, 4.1666666666666664e-02);
    p = fma(p, f, 1.6666666666666666e-01);
    p = fma(p, f, 5.0e-01);
    double r = fma(f * f, p, f) + 1.0;
    return ldexp(r, (int)n);
}

// ---- inline f64 log: rel err ~1e-13, x > 0 normal ---------------------------
__device__ __forceinline__ double flog(double x) {
    int e;
    double mant = frexp(x, &e);            // [0.5, 1)
    if (mant < 0.70710678118654752) { mant += mant; e -= 1; }
    double u  = (mant - 1.0) / (mant + 1.0);
    double u2 = u * u;
    double p = 1.0 / 13.0;
    p = fma(p, u2, 1.0 / 11.0);
    p = fma(p, u2, 1.0 / 9.0);
    p = fma(p, u2, 1.0 / 7.0);
    p = fma(p, u2, 1.0 / 5.0);
    p = fma(p, u2, 1.0 / 3.0);
    p = fma(p, u2, 1.0);
    return fma((double)e, 0.69314718055994530942, 2.0 * u * p);
}

// ---------------- Kernel A: count histogram -> per-block partials -----------
__global__ __launch_bounds__(1024) void k_hist(const float4* __restrict__ v4, int n4,
                                               unsigned* __restrict__ gpart,
                                               unsigned* __restrict__ counter) {
    __shared__ unsigned h[NBINS];
    for (int i = threadIdx.x; i < NBINS; i += 1024) h[i] = 0u;
    __syncthreads();

    const int stride = gridDim.x * 1024;
    for (int i = blockIdx.x * 1024 + threadIdx.x; i < n4; i += stride) {
        float4 x = v4[i];
        float vals[4] = {x.x, x.y, x.z, x.w};
#pragma unroll
        for (int k = 0; k < 4; ++k) {
            float pos = fmaf(vals[k], F_INVW, 1024.0f);       // (v+8)*128
            pos = fminf(fmaxf(pos, 0.0f), 2047.0f);
            atomicAdd(&h[(int)pos], 1u);
        }
    }
    __syncthreads();
    unsigned* dst = gpart + (size_t)blockIdx.x * NBINS;
    for (int i = threadIdx.x; i < NBINS; i += 1024) dst[i] = h[i];
    // re-arm the completion counter for this launch (kernel-boundary visible)
    if (blockIdx.x == 0 && threadIdx.x == 0) *counter = 0u;
}

// ---------------- Kernel B: reduce partials; last block solves --------------
__global__ __launch_bounds__(256) void k_reduce_solve(const unsigned* __restrict__ gpart,
                                                      unsigned* __restrict__ gcnt,
                                                      unsigned* __restrict__ counter,
                                                      float* __restrict__ out) {
    __shared__ unsigned rc[16][16];
    __shared__ double pc[NBINS];   // inclusive prefix of counts
    __shared__ double ps[NBINS];   // inclusive prefix of S = sum exp(10 v)
    __shared__ double wtc[4], wts[4];
    __shared__ double ra[4], rb[4], rq3[4];
    __shared__ double sh_eta;
    __shared__ int lastf;

    const int t = threadIdx.x;

    // ---- phase 1: reduce HB slices for this block's 16 bins ----
    {
        const int bl  = t & 15;
        const int row = t >> 4;                     // 0..15
        const int bin = blockIdx.x * 16 + bl;
        unsigned c = 0;
        for (int s = row; s < HB; s += 16)
            c += gpart[(size_t)s * NBINS + bin];
        rc[row][bl] = c;
    }
    __syncthreads();
    // wave 0 only: final per-bin sums -> agent-scope stores -> counter RMW.
    // Stores and the RMW are issued by the same wave in program order; the
    // ACQ_REL RMW's release side waits the wave's outstanding vmem (vmcnt),
    // so gcnt is device-visible before any block can observe the increment.
    if (t < 16) {
        unsigned ct = 0;
#pragma unroll
        for (int k = 0; k < 16; ++k) ct += rc[k][t];
        __hip_atomic_store(&gcnt[blockIdx.x * 16 + t], ct,
                           __ATOMIC_RELAXED, __HIP_MEMORY_SCOPE_AGENT);
    }
    if (t == 0)
        lastf = (__hip_atomic_fetch_add(counter, 1u, __ATOMIC_ACQ_REL,
                                        __HIP_MEMORY_SCOPE_AGENT) == RB - 1) ? 1 : 0;
    __syncthreads();
    if (!lastf) return;

    // ---- phase 2 (one block, 256 threads): scan + bisection + loss ----
    const int lane = t & 63;
    const int wid  = t >> 6;
    const double ewr = fexp(D_WR);
    const double KS  = (ewr - 1.0) / D_WR;          // uniform-in-bin exp average

    double cc = 0.0, ss = 0.0, thr_c, thr_s;
    {
        unsigned cu[8];
#pragma unroll
        for (int i = 0; i < 8; ++i)
            cu[i] = __hip_atomic_load(&gcnt[t * 8 + i], __ATOMIC_RELAXED,
                                      __HIP_MEMORY_SCOPE_AGENT);
#pragma unroll
        for (int i = 0; i < 8; ++i) {
            const int bin = t * 8 + i;
            double c = (double)cu[i];
            double S = c * KS * fexp(10.0 * (D_LO + (double)bin * D_W));
            cc += c; ss += S;
            pc[bin] = cc; ps[bin] = ss;             // thread-local inclusive
        }
        thr_c = cc; thr_s = ss;
    }
    // intra-wave inclusive scan of thread totals
#pragma unroll
    for (int off = 1; off < 64; off <<= 1) {
        double nc = __shfl_up(cc, off, 64);
        double ns = __shfl_up(ss, off, 64);
        if (lane >= off) { cc += nc; ss += ns; }
    }
    if (lane == 63) { wtc[wid] = cc; wts[wid] = ss; }
    __syncthreads();                                // b1
    {
        double woc = 0.0, wos = 0.0;
        for (int k = 0; k < wid; ++k) { woc += wtc[k]; wos += wts[k]; }
        double exc_c = cc - thr_c + woc;            // prefix before my bins
        double exc_s = ss - thr_s + wos;
#pragma unroll
        for (int i = 0; i < 8; ++i) { pc[t * 8 + i] += exc_c; ps[t * 8 + i] += exc_s; }
    }
    __syncthreads();                                // b2

    const double m    = pc[NBINS - 1];
    const double Stot = ps[NBINS - 1];

    // ---- wave 0: 65-ary bisection for eta ----
    if (t < 64) {
        const double inv_ewrm1 = 1.0 / (ewr - 1.0);
        const double inv_m = 1.0 / m;

        auto feval = [&](double eta) -> double {
            double c = eta + D_REG * D_LN10;        // clamp boundary in v-space
            double Cle, Sle;
            if (c <= D_LO) { Cle = 0.0; Sle = 0.0; }
            else {
                double pos = (c - D_LO) * (1.0 / D_W);
                if (pos >= (double)NBINS) { Cle = m; Sle = Stot; }
                else {
                    int j = (int)pos;
                    double ttf = pos - (double)j;
                    double pcm = j > 0 ? pc[j - 1] : 0.0;
                    double psm = j > 0 ? ps[j - 1] : 0.0;
                    double cj = pc[j] - pcm;
                    double sj = ps[j] - psm;
                    double frac = (fexp(ttf * D_WR) - 1.0) * inv_ewrm1;
                    Cle = pcm + ttf * cj;
                    Sle = psm + frac * sj;
                }
            }
            return 1.0 - (10.0 * (m - Cle) + fexp(-eta * 10.0) * Sle) * inv_m;
        };

        double eta_min = D_REG * (flog(Stot) - flog(m));
        double f_emin  = feval(eta_min);

        double lo = -12.0;   // f(lo) = -9 < 0
        double hi =  20.0;   // f(hi) ~ 1 > 0
        for (int r = 0; r < 4; ++r) {               // bracket -> 32/65^4 ~ 1.8e-6
            double step = (hi - lo) * (1.0 / 65.0);
            double x = lo + step * (double)(t + 1);
            double fx = feval(x);
            unsigned long long mpos = __ballot(fx > 0.0);
            int k = mpos ? __builtin_ctzll(mpos) : 64;
            double nlo = lo + step * (double)k;
            double nhi = (k >= 64) ? hi : lo + step * (double)(k + 1);
            lo = nlo; hi = nhi;
        }
        double eta = 0.5 * (lo + hi);
        if (fabs(f_emin) <= D_TOL) eta = eta_min;
        if (t == 0) sh_eta = eta;
    }
    __syncthreads();                                // b3

    // ---- all 256 threads: loss moment sums (bins recovered from pc/ps) ----
    const double eta  = sh_eta;
    const double MU_W = D_W * ewr / (ewr - 1.0) - D_REG;   // exp-weighted mean offset

    double cb  = eta + D_REG * D_LN10;
    double pos = (cb - D_LO) * (1.0 / D_W);
    pos = fmin(fmax(pos, 0.0), (double)NBINS);
    int jb = (int)pos;                       // boundary bin (== NBINS: none clamped)
    double ttf = pos - (double)jb;

    double Vt = 0.0, Vb = 0.0, Tb = 0.0;
#pragma unroll
    for (int i = 0; i < 8; ++i) {
        const int bin = t * 8 + i;
        double pcm_ = bin ? pc[bin - 1] : 0.0;
        double c    = pc[bin] - pcm_;
        double bb   = D_LO + (double)bin * D_W;
        double vmid = bb + 0.5 * D_W;
        Vt += c * vmid;
        if (bin < jb) {
            double S = ps[bin] - (bin ? ps[bin - 1] : 0.0);
            Vb += c * vmid;
            Tb += S * (bb + MU_W);
        }
    }
#pragma unroll
    for (int off = 32; off >= 1; off >>= 1) {
        Vt += __shfl_down(Vt, off, 64);
        Vb += __shfl_down(Vb, off, 64);
        Tb += __shfl_down(Tb, off, 64);
    }
    if (lane == 0) { ra[wid] = Vt; rb[wid] = Vb; rq3[wid] = Tb; }
    __syncthreads();                                // b4

    if (t == 0) {
        double Vtot = ra[0] + ra[1] + ra[2] + ra[3];
        double Vle  = rb[0] + rb[1] + rb[2] + rb[3];
        double Tle  = rq3[0] + rq3[1] + rq3[2] + rq3[3];
        double pcm = jb > 0 ? pc[jb - 1] : 0.0;
        double psm = jb > 0 ? ps[jb - 1] : 0.0;
        double Cle = pcm, Sle = psm;
        if (jb < NBINS) {                    // boundary-bin partial contributions
            double cj = pc[jb] - pcm;
            double sj = ps[jb] - psm;
            double bbj = D_LO + (double)jb * D_W;
            double x = ttf * D_W;
            double frac = 0.0, mu = 0.0;
            if (x > 1e-14) {
                double e = fexp(x * 10.0);
                frac = (e - 1.0) / (ewr - 1.0);
                mu   = x * e / (e - 1.0) - D_REG;
            }
            Cle += ttf * cj;
            Sle += frac * sj;
            Tle += frac * sj * (bbj + mu);
            Vle += ttf * cj * (bbj + 0.5 * x);
        }
        double em    = fexp(-eta * 10.0);
        double inv_m = 1.0 / m;
        double lnm   = flog(m);
        double Q  = em * Sle + 10.0 * (m - Cle);               // sum q
        double A  = em * Tle + 10.0 * (Vtot - Vle);            // sum q v
        double B  = 10.0 * (em * Tle - eta * em * Sle)         // sum q ln q
                  + 10.0 * D_LN10 * (m - Cle);
        double plogp = B * inv_m - lnm * (Q * inv_m);
        double loss  = A * inv_m - D_REG * (lnm + plogp);
        out[0] = (float)loss;
    }
}

// ---------------------------------------------------------------------------
extern "C" void kernel_launch(void* const* d_in, const int* in_sizes, int n_in,
                              void* d_out, int out_size, void* d_ws, size_t ws_size,
                              hipStream_t stream) {
    const float* v = (const float*)d_in[0];
    const int n  = in_sizes[0];      // 16777216
    const int n4 = n / 4;

    char* ws = (char*)d_ws;
    unsigned* gpart   = (unsigned*)ws;                              // HB*NBINS u32 = 4 MB
    unsigned* gcnt    = (unsigned*)(ws + (size_t)HB * NBINS * 4);   // NBINS u32
    unsigned* counter = gcnt + NBINS;                               // 1 u32

    k_hist        <<<HB, 1024, 0, stream>>>((const float4*)v, n4, gpart, counter);
    k_reduce_solve<<<RB, 256,  0, stream>>>(gpart, gcnt, counter, (float*)d_out);
}

// Round 8
// 27.915 us; speedup vs baseline: 1.2575x; 1.1625x over previous
//
#include <hip/hip_runtime.h>
#include <math.h>

// ---------------------------------------------------------------------------
// RobustLoss: CVaR (alpha=0.1) best-response with entropy reg (REG=0.1) on
// M = 2^24 f32 values, returning scalar  p.v - REG*KL(p,uniform).
//
// THREE kernels, single data pass (kernel boundaries provide the global
// release/acquire for free — measured cheaper than any in-kernel protocol):
//   k_hist   : LDS count histogram, NT float4 loads, u16-packed partials
//   k_reduce : sum 512 partial histograms -> per-bin u32 counts
//   k_solve  : wave-scan + 65-ary bisection -> eta; loss from histogram
//              moments (uniform-in-bin exp interpolation), all inline f64.
// ---------------------------------------------------------------------------

#define NBINS 2048
#define HB    512      // hist blocks (partial histograms); per-block count <= 32768 -> u16 safe
#define RBLK  64       // reduce blocks (16 bin-pairs each)

typedef float f32x4 __attribute__((ext_vector_type(4)));

static constexpr float  F_INVW  = 128.0f;         // 1 / bin width
static constexpr double D_LO    = -8.0;
static constexpr double D_W     = 0.0078125;      // 16 / 2048
static constexpr double D_REG   = 0.1;
static constexpr double D_WR    = 0.078125;       // D_W / D_REG
static constexpr double D_TOL   = 1e-4;
static constexpr double D_LN10  = 2.302585092994045684;

// ---- inline f64 exp: rel err ~1e-14, no libm calls -------------------------
__device__ __forceinline__ double fexp(double x) {
    const double LOG2E = 1.4426950408889634074;
    const double LN2HI = 6.93147180369123816490e-01;
    const double LN2LO = 1.90821492927058770002e-10;
    double n = rint(x * LOG2E);
    double f = fma(-n, LN2HI, x);
    f = fma(-n, LN2LO, f);                 // |f| <= 0.3466
    double p = 2.08767569878681e-09;       // 1/12!
    p = fma(p, f, 2.5052108385441718e-08);
    p = fma(p, f, 2.7557319223985891e-07);
    p = fma(p, f, 2.7557319223985893e-06);
    p = fma(p, f, 2.4801587301587302e-05);
    p = fma(p, f, 1.9841269841269841e-04);
    p = fma(p, f, 1.3888888888888889e-03);
    p = fma(p, f, 8.3333333333333332e-03);
    p = fma(p, f, 4.1666666666666664e-02);
    p = fma(p, f, 1.6666666666666666e-01);
    p = fma(p, f, 5.0e-01);
    double r = fma(f * f, p, f) + 1.0;
    return ldexp(r, (int)n);
}

// ---- inline f64 log: rel err ~1e-13, x > 0 normal ---------------------------
__device__ __forceinline__ double flog(double x) {
    int e;
    double mant = frexp(x, &e);            // [0.5, 1)
    if (mant < 0.70710678118654752) { mant += mant; e -= 1; }
    double u  = (mant - 1.0) / (mant + 1.0);
    double u2 = u * u;
    double p = 1.0 / 13.0;
    p = fma(p, u2, 1.0 / 11.0);
    p = fma(p, u2, 1.0 / 9.0);
    p = fma(p, u2, 1.0 / 7.0);
    p = fma(p, u2, 1.0 / 5.0);
    p = fma(p, u2, 1.0 / 3.0);
    p = fma(p, u2, 1.0);
    return fma((double)e, 0.69314718055994530942, 2.0 * u * p);
}

// ---------------- Kernel A: count histogram -> u16-packed partials ----------
__global__ __launch_bounds__(1024) void k_hist(const f32x4* __restrict__ v4, int n4,
                                               unsigned* __restrict__ gpart) {
    __shared__ unsigned h[NBINS];
    for (int i = threadIdx.x; i < NBINS; i += 1024) h[i] = 0u;
    __syncthreads();

    const int stride = gridDim.x * 1024;
    int i = blockIdx.x * 1024 + threadIdx.x;
    for (; i + stride < n4; i += 2 * stride) {        // 2 independent 16B loads in flight
        f32x4 a = __builtin_nontemporal_load(&v4[i]);
        f32x4 b = __builtin_nontemporal_load(&v4[i + stride]);
#pragma unroll
        for (int k = 0; k < 4; ++k) {
            float pa = fminf(fmaxf(fmaf(a[k], F_INVW, 1024.0f), 0.0f), 2047.0f);
            atomicAdd(&h[(int)pa], 1u);
        }
#pragma unroll
        for (int k = 0; k < 4; ++k) {
            float pb = fminf(fmaxf(fmaf(b[k], F_INVW, 1024.0f), 0.0f), 2047.0f);
            atomicAdd(&h[(int)pb], 1u);
        }
    }
    for (; i < n4; i += stride) {
        f32x4 a = __builtin_nontemporal_load(&v4[i]);
#pragma unroll
        for (int k = 0; k < 4; ++k) {
            float pa = fminf(fmaxf(fmaf(a[k], F_INVW, 1024.0f), 0.0f), 2047.0f);
            atomicAdd(&h[(int)pa], 1u);
        }
    }
    __syncthreads();
    // pack bins (2b, 2b+1) -> one u32 (per-block per-bin count < 2^16)
    unsigned* dst = gpart + (size_t)blockIdx.x * (NBINS / 2);
    for (int p = threadIdx.x; p < NBINS / 2; p += 1024)
        dst[p] = (h[2 * p] & 0xFFFFu) | (h[2 * p + 1] << 16);
}

// ---------------- Kernel B: reduce HB u16-packed partials -> u32 counts -----
// Grid: RBLK=64 blocks, 16 bin-pairs each; 256 thr = 16 rows x 16 pair-lanes.
__global__ __launch_bounds__(256) void k_reduce(const unsigned* __restrict__ gpart,
                                                unsigned* __restrict__ gcnt) {
    __shared__ unsigned r0[16][16];
    __shared__ unsigned r1[16][16];
    const int pl   = threadIdx.x & 15;
    const int row  = threadIdx.x >> 4;
    const int pcol = blockIdx.x * 16 + pl;            // 0..1023

    unsigned c0 = 0, c1 = 0;
    for (int s = row; s < HB; s += 16) {              // 32 loads, unpack u16 pair
        unsigned pk = gpart[(size_t)s * (NBINS / 2) + pcol];
        c0 += pk & 0xFFFFu;
        c1 += pk >> 16;
    }
    r0[row][pl] = c0; r1[row][pl] = c1;
    __syncthreads();
    if (threadIdx.x < 16) {
        unsigned t0 = 0, t1 = 0;
#pragma unroll
        for (int k = 0; k < 16; ++k) { t0 += r0[k][threadIdx.x]; t1 += r1[k][threadIdx.x]; }
        const int pc2 = blockIdx.x * 16 + threadIdx.x;
        gcnt[2 * pc2]     = t0;
        gcnt[2 * pc2 + 1] = t1;
    }
}

// ---------------- Kernel C: scan + bisection + loss -> out ------------------
__global__ __launch_bounds__(256) void k_solve(const unsigned* __restrict__ gcnt,
                                               float* __restrict__ out) {
    __shared__ double pc[NBINS];   // inclusive prefix of counts
    __shared__ double ps[NBINS];   // inclusive prefix of S = sum exp(10 v)
    __shared__ double wtc[4], wts[4];
    __shared__ double ra[4], rb[4], rq3[4];
    __shared__ double sh_eta;

    const int t    = threadIdx.x;
    const int lane = t & 63;
    const int wid  = t >> 6;

    const uint4* c4 = reinterpret_cast<const uint4*>(gcnt);
    uint4 ca = c4[2 * t], cb2 = c4[2 * t + 1];
    unsigned cu[8] = {ca.x, ca.y, ca.z, ca.w, cb2.x, cb2.y, cb2.z, cb2.w};

    const double ewr = fexp(D_WR);                 // e^{W/REG} (also bin-to-bin S ratio)
    const double KS  = (ewr - 1.0) / D_WR;         // uniform-in-bin exp average

    // S_bin = cnt * KS * e^{10*(LO + bin*W)}: one fexp + geometric ratio
    double E = KS * fexp(10.0 * (D_LO + (double)(t * 8) * D_W));
    double cc = 0.0, ss = 0.0;
#pragma unroll
    for (int i = 0; i < 8; ++i) {
        double c = (double)cu[i];
        double S = c * E;
        E *= ewr;
        cc += c; ss += S;
        pc[t * 8 + i] = cc; ps[t * 8 + i] = ss;    // thread-local inclusive
    }
    const double thr_c = cc, thr_s = ss;

    // intra-wave inclusive scan of thread totals
#pragma unroll
    for (int off = 1; off < 64; off <<= 1) {
        double nc = __shfl_up(cc, off, 64);
        double ns = __shfl_up(ss, off, 64);
        if (lane >= off) { cc += nc; ss += ns; }
    }
    if (lane == 63) { wtc[wid] = cc; wts[wid] = ss; }
    __syncthreads();                                // b1
    {
        double woc = 0.0, wos = 0.0;
        for (int k = 0; k < wid; ++k) { woc += wtc[k]; wos += wts[k]; }
        double exc_c = cc - thr_c + woc;            // prefix before my bins
        double exc_s = ss - thr_s + wos;
#pragma unroll
        for (int i = 0; i < 8; ++i) { pc[t * 8 + i] += exc_c; ps[t * 8 + i] += exc_s; }
    }
    __syncthreads();                                // b2

    const double m    = pc[NBINS - 1];
    const double Stot = ps[NBINS - 1];

    // ---- wave 0: 65-ary bisection for eta ----
    if (t < 64) {
        const double inv_ewrm1 = 1.0 / (ewr - 1.0);
        const double inv_m = 1.0 / m;

        auto feval = [&](double eta) -> double {
            double c = eta + D_REG * D_LN10;        // clamp boundary in v-space
            double Cle, Sle;
            if (c <= D_LO) { Cle = 0.0; Sle = 0.0; }
            else {
                double pos = (c - D_LO) * (1.0 / D_W);
                if (pos >= (double)NBINS) { Cle = m; Sle = Stot; }
                else {
                    int j = (int)pos;
                    double ttf = pos - (double)j;
                    double pcm = j > 0 ? pc[j - 1] : 0.0;
                    double psm = j > 0 ? ps[j - 1] : 0.0;
                    double cj = pc[j] - pcm;
                    double sj = ps[j] - psm;
                    double frac = (fexp(ttf * D_WR) - 1.0) * inv_ewrm1;
                    Cle = pcm + ttf * cj;
                    Sle = psm + frac * sj;
                }
            }
            return 1.0 - (10.0 * (m - Cle) + fexp(-eta * 10.0) * Sle) * inv_m;
        };

        double eta_min = D_REG * (flog(Stot) - flog(m));
        double f_emin  = feval(eta_min);

        double lo = -12.0;   // f(lo) = -9 < 0
        double hi =  20.0;   // f(hi) ~ 1 > 0
        for (int r = 0; r < 4; ++r) {               // bracket -> 32/65^4 ~ 1.8e-6
            double step = (hi - lo) * (1.0 / 65.0);
            double x = lo + step * (double)(t + 1);
            double fx = feval(x);
            unsigned long long mpos = __ballot(fx > 0.0);
            int k = mpos ? __builtin_ctzll(mpos) : 64;
            double nlo = lo + step * (double)k;
            double nhi = (k >= 64) ? hi : lo + step * (double)(k + 1);
            lo = nlo; hi = nhi;
        }
        double eta = 0.5 * (lo + hi);
        if (fabs(f_emin) <= D_TOL) eta = eta_min;
        if (t == 0) sh_eta = eta;
    }
    __syncthreads();                                // b3

    // ---- all 256 threads: loss moment sums (bins recovered from pc/ps) ----
    const double eta  = sh_eta;
    const double MU_W = D_W * ewr / (ewr - 1.0) - D_REG;   // exp-weighted mean offset

    double cb  = eta + D_REG * D_LN10;
    double pos = (cb - D_LO) * (1.0 / D_W);
    pos = fmin(fmax(pos, 0.0), (double)NBINS);
    int jb = (int)pos;                       // boundary bin (== NBINS: none clamped)
    double ttf = pos - (double)jb;

    double Vt = 0.0, Vb = 0.0, Tb = 0.0;
#pragma unroll
    for (int i = 0; i < 8; ++i) {
        const int bin = t * 8 + i;
        double pcm_ = bin ? pc[bin - 1] : 0.0;
        double c    = pc[bin] - pcm_;
        double bb   = D_LO + (double)bin * D_W;
        double vmid = bb + 0.5 * D_W;
        Vt += c * vmid;
        if (bin < jb) {
            double S = ps[bin] - (bin ? ps[bin - 1] : 0.0);
            Vb += c * vmid;
            Tb += S * (bb + MU_W);
        }
    }
#pragma unroll
    for (int off = 32; off >= 1; off >>= 1) {
        Vt += __shfl_down(Vt, off, 64);
        Vb += __shfl_down(Vb, off, 64);
        Tb += __shfl_down(Tb, off, 64);
    }
    if (lane == 0) { ra[wid] = Vt; rb[wid] = Vb; rq3[wid] = Tb; }
    __syncthreads();                                // b4

    if (t == 0) {
        double Vtot = ra[0] + ra[1] + ra[2] + ra[3];
        double Vle  = rb[0] + rb[1] + rb[2] + rb[3];
        double Tle  = rq3[0] + rq3[1] + rq3[2] + rq3[3];
        double pcm = jb > 0 ? pc[jb - 1] : 0.0;
        double psm = jb > 0 ? ps[jb - 1] : 0.0;
        double Cle = pcm, Sle = psm;
        if (jb < NBINS) {                    // boundary-bin partial contributions
            double cj = pc[jb] - pcm;
            double sj = ps[jb] - psm;
            double bbj = D_LO + (double)jb * D_W;
            double x = ttf * D_W;
            double frac = 0.0, mu = 0.0;
            if (x > 1e-14) {
                double e = fexp(x * 10.0);
                frac = (e - 1.0) / (ewr - 1.0);
                mu   = x * e / (e - 1.0) - D_REG;
            }
            Cle += ttf * cj;
            Sle += frac * sj;
            Tle += frac * sj * (bbj + mu);
            Vle += ttf * cj * (bbj + 0.5 * x);
        }
        double em    = fexp(-eta * 10.0);
        double inv_m = 1.0 / m;
        double lnm   = flog(m);
        double Q  = em * Sle + 10.0 * (m - Cle);               // sum q
        double A  = em * Tle + 10.0 * (Vtot - Vle);            // sum q v
        double B  = 10.0 * (em * Tle - eta * em * Sle)         // sum q ln q
                  + 10.0 * D_LN10 * (m - Cle);
        double plogp = B * inv_m - lnm * (Q * inv_m);
        double loss  = A * inv_m - D_REG * (lnm + plogp);
        out[0] = (float)loss;
    }
}

// ---------------------------------------------------------------------------
extern "C" void kernel_launch(void* const* d_in, const int* in_sizes, int n_in,
                              void* d_out, int out_size, void* d_ws, size_t ws_size,
                              hipStream_t stream) {
    const float* v = (const float*)d_in[0];
    const int n  = in_sizes[0];      // 16777216
    const int n4 = n / 4;

    char* ws = (char*)d_ws;
    unsigned* gpart = (unsigned*)ws;                               // HB*1024 u32 = 2 MB
    unsigned* gcnt  = (unsigned*)(ws + (size_t)HB * (NBINS / 2) * 4);  // NBINS u32

    k_hist  <<<HB,   1024, 0, stream>>>((const f32x4*)v, n4, gpart);
    k_reduce<<<RBLK, 256,  0, stream>>>(gpart, gcnt);
    k_solve <<<1,    256,  0, stream>>>(gcnt, (float*)d_out);
}